// Round 1
// baseline (318.602 us; speedup 1.0000x reference)
//
#include <hip/hip_runtime.h>

typedef short bfrag __attribute__((ext_vector_type(8)));   // 8 bf16 (4 VGPRs)
typedef float f32x4 __attribute__((ext_vector_type(4)));   // MFMA accumulator

#define MFMA16(a, b, c) __builtin_amdgcn_mfma_f32_16x16x32_bf16((a), (b), (c), 0, 0, 0)

// ---- constants for this problem ----
// b=2, s=2048, d=1024, h=16, hd=64, R=257, w=128, scale=sqrt(64)=8
#define SEQ   2048
#define DMOD  1024
#define NHEAD 16
#define HDIM  64
#define NBH   32      // b*h
#define RSZ   257
#define RPADN 272     // 17*16, zero-padded

__device__ __forceinline__ unsigned short f2bf(float f) {
  unsigned int u = __float_as_uint(f);
  u += 0x7FFFu + ((u >> 16) & 1u);   // round-to-nearest-even
  return (unsigned short)(u >> 16);
}

__device__ __forceinline__ void gl2lds16(const void* g, void* l) {
  __builtin_amdgcn_global_load_lds(
      (__attribute__((address_space(1))) void*)(g),
      (__attribute__((address_space(3))) void*)(l), 16, 0, 0);
}

// ------------------- cast kernels -------------------
__global__ __launch_bounds__(256) void cast_bf16(const float* __restrict__ src,
                                                 unsigned short* __restrict__ dst,
                                                 int n) {
  int i = (blockIdx.x * 256 + threadIdx.x) * 4;
  if (i >= n) return;
  float4 v = *(const float4*)(src + i);
  ushort4 o;
  o.x = f2bf(v.x); o.y = f2bf(v.y); o.z = f2bf(v.z); o.w = f2bf(v.w);
  *(ushort4*)(dst + i) = o;
}

// Wr [257][64] -> bf16 padded to [272][64] (rows >=257 zero)
__global__ __launch_bounds__(256) void cast_wr(const float* __restrict__ src,
                                               unsigned short* __restrict__ dst) {
  int i = blockIdx.x * 256 + threadIdx.x;
  if (i >= RPADN * HDIM) return;
  int r = i / HDIM;
  float v = (r < RSZ) ? src[i] : 0.0f;
  dst[i] = f2bf(v);
}

// ------------------- QKV projection GEMM -------------------
// C[m,n] = sum_k xb[m,k] * wb[n,k] + bqkv[n],  m in [0,4096), n in [0,3072), K=1024.
// 128x128 tile per block, BK=64, 256 threads (2x2 waves of 4x4 16x16 MFMA tiles).
// Epilogue scatters into q[bh][s][64], k[bh][s][64], vT[bh][64][s] (bf16).
__global__ __launch_bounds__(256) void qkv_gemm(const unsigned short* __restrict__ xb,
                                                const unsigned short* __restrict__ wb,
                                                const float* __restrict__ bqkv,
                                                unsigned short* __restrict__ qb,
                                                unsigned short* __restrict__ kbuf,
                                                unsigned short* __restrict__ vtb) {
  __shared__ unsigned short As[128 * 64];
  __shared__ unsigned short Bs[128 * 64];
  const int tid = threadIdx.x;
  const int m0 = blockIdx.y * 128, n0 = blockIdx.x * 128;
  const int wave = tid >> 6, lane = tid & 63;
  const int q4 = lane >> 4, l16 = lane & 15;
  const int wm = (wave & 1) * 64, wn = (wave >> 1) * 64;

  f32x4 acc[4][4];
#pragma unroll
  for (int rt = 0; rt < 4; ++rt)
#pragma unroll
    for (int ct = 0; ct < 4; ++ct) acc[rt][ct] = (f32x4){0.f, 0.f, 0.f, 0.f};

  for (int k0 = 0; k0 < DMOD; k0 += 64) {
#pragma unroll
    for (int it = 0; it < 4; ++it) {
      int ch = it * 256 + tid;
      int r = ch >> 3, c = ch & 7;
      gl2lds16(xb + (size_t)(m0 + r) * DMOD + k0 + c * 8, As + ch * 8);
      gl2lds16(wb + (size_t)(n0 + r) * DMOD + k0 + c * 8, Bs + ch * 8);
    }
    __syncthreads();
#pragma unroll
    for (int ks = 0; ks < 2; ++ks) {
      bfrag af[4], bf[4];
#pragma unroll
      for (int rt = 0; rt < 4; ++rt)
        af[rt] = *(const bfrag*)(As + (wm + rt * 16 + l16) * 64 + ks * 32 + q4 * 8);
#pragma unroll
      for (int ct = 0; ct < 4; ++ct)
        bf[ct] = *(const bfrag*)(Bs + (wn + ct * 16 + l16) * 64 + ks * 32 + q4 * 8);
#pragma unroll
      for (int rt = 0; rt < 4; ++rt)
#pragma unroll
        for (int ct = 0; ct < 4; ++ct)
          acc[rt][ct] = MFMA16(af[rt], bf[ct], acc[rt][ct]);
    }
    __syncthreads();
  }

#pragma unroll
  for (int rt = 0; rt < 4; ++rt) {
#pragma unroll
    for (int ct = 0; ct < 4; ++ct) {
      int n = n0 + wn + ct * 16 + l16;
      int hh = n / 192;
      int rem = n - hh * 192;
      int t = rem >> 6, dd = rem & 63;
      float bias = bqkv[n];
#pragma unroll
      for (int reg = 0; reg < 4; ++reg) {
        int m = m0 + wm + rt * 16 + q4 * 4 + reg;
        int bidx = m >> 11, sidx = m & 2047;
        unsigned short bv = f2bf(acc[rt][ct][reg] + bias);
        size_t hb = (size_t)(bidx * NHEAD + hh);
        if (t == 0)      qb  [(hb * SEQ + sidx) * HDIM + dd] = bv;
        else if (t == 1) kbuf[(hb * SEQ + sidx) * HDIM + dd] = bv;
        else             vtb [(hb * HDIM + dd) * SEQ + sidx] = bv;
      }
    }
  }
}

// ------------------- rel-pos logits GEMM -------------------
// rp[row, r] = sum_d q[row,d]*Wr[r,d] + br[r];  rows = bh*2048+i (65536), N=257 (pad 272), K=64
__global__ __launch_bounds__(256) void rp_gemm(const unsigned short* __restrict__ qb,
                                               const unsigned short* __restrict__ wrb,
                                               const float* __restrict__ br,
                                               float* __restrict__ rp) {
  __shared__ unsigned short WrS[RPADN * HDIM];  // 34816 B
  __shared__ unsigned short Qs[64 * HDIM];      // 8192 B
  const int tid = threadIdx.x;
  const size_t row0 = (size_t)blockIdx.x * 64;

  for (int i = tid; i < RPADN * HDIM / 8; i += 256)
    *(uint4*)(&WrS[i * 8]) = *(const uint4*)(&wrb[i * 8]);
  for (int i = tid; i < 512; i += 256)
    *(uint4*)(&Qs[i * 8]) = *(const uint4*)(&qb[row0 * HDIM + i * 8]);
  __syncthreads();

  const int wave = tid >> 6, lane = tid & 63;
  const int q4 = lane >> 4, l16 = lane & 15;

  bfrag af0 = *(const bfrag*)(Qs + (wave * 16 + l16) * 64 + q4 * 8);
  bfrag af1 = *(const bfrag*)(Qs + (wave * 16 + l16) * 64 + 32 + q4 * 8);

#pragma unroll 4
  for (int ct = 0; ct < 17; ++ct) {
    f32x4 acc = (f32x4){0.f, 0.f, 0.f, 0.f};
    bfrag b0 = *(const bfrag*)(WrS + (ct * 16 + l16) * 64 + q4 * 8);
    bfrag b1 = *(const bfrag*)(WrS + (ct * 16 + l16) * 64 + 32 + q4 * 8);
    acc = MFMA16(af0, b0, acc);
    acc = MFMA16(af1, b1, acc);
    int col = ct * 16 + l16;
    if (col < RSZ) {
      float bias = br[col];
#pragma unroll
      for (int reg = 0; reg < 4; ++reg) {
        size_t rr = row0 + wave * 16 + q4 * 4 + reg;
        rp[rr * RSZ + col] = acc[reg] + bias;
      }
    }
  }
}

// ------------------- flash attention with relative position -------------------
// grid (32 qtiles, 32 bh); 256 thr; wave w owns Q rows [w*16, w*16+16); BN=64.
__global__ __launch_bounds__(256) void flash_attn(const unsigned short* __restrict__ qb,
                                                  const unsigned short* __restrict__ kbuf,
                                                  const unsigned short* __restrict__ vtb,
                                                  const float* __restrict__ rp,
                                                  float* __restrict__ out) {
  __shared__ unsigned short Ks[64 * 64];
  __shared__ unsigned short Vs[64 * 64];   // [d][j] (transposed V tile)
  __shared__ unsigned short Ps[64 * 72];   // padded stride 72 (144 B, 16B-aligned)

  const int tid = threadIdx.x;
  const int i0 = blockIdx.x * 64;
  const int bh = blockIdx.y;
  const int wave = tid >> 6, lane = tid & 63;
  const int q4 = lane >> 4, l16 = lane & 15;

  const unsigned short* qrow = qb + ((size_t)bh * SEQ + i0 + wave * 16 + l16) * HDIM;
  bfrag qf0 = *(const bfrag*)(qrow + q4 * 8);
  bfrag qf1 = *(const bfrag*)(qrow + 32 + q4 * 8);

  const float* rpb = rp + (size_t)bh * SEQ * RSZ;
  int irow[4];
  float rpL[4], rpR[4];
#pragma unroll
  for (int reg = 0; reg < 4; ++reg) {
    irow[reg] = i0 + wave * 16 + q4 * 4 + reg;
    rpL[reg] = rpb[(size_t)irow[reg] * RSZ];
    rpR[reg] = rpb[(size_t)irow[reg] * RSZ + 256];
  }

  float m_s[4], l_s[4];
  f32x4 oacc[4];
#pragma unroll
  for (int reg = 0; reg < 4; ++reg) { m_s[reg] = -3.0e38f; l_s[reg] = 0.f; }
#pragma unroll
  for (int ct = 0; ct < 4; ++ct) oacc[ct] = (f32x4){0.f, 0.f, 0.f, 0.f};

  const unsigned short* kbase = kbuf + (size_t)bh * SEQ * HDIM;
  const unsigned short* vbase = vtb + (size_t)bh * HDIM * SEQ;

  for (int jt = 0; jt < 32; ++jt) {
    const int j0 = jt * 64;
#pragma unroll
    for (int it = 0; it < 2; ++it) {
      int ch = it * 256 + tid;
      int r = ch >> 3, c = ch & 7;
      gl2lds16(kbase + (size_t)(j0 + r) * HDIM + c * 8, Ks + ch * 8);
      gl2lds16(vbase + (size_t)r * SEQ + j0 + c * 8, Vs + ch * 8);
    }
    __syncthreads();

    // S = Q K^T
    f32x4 sacc[4];
#pragma unroll
    for (int ct = 0; ct < 4; ++ct) {
      sacc[ct] = (f32x4){0.f, 0.f, 0.f, 0.f};
      bfrag k0f = *(const bfrag*)(Ks + (ct * 16 + l16) * 64 + q4 * 8);
      bfrag k1f = *(const bfrag*)(Ks + (ct * 16 + l16) * 64 + 32 + q4 * 8);
      sacc[ct] = MFMA16(qf0, k0f, sacc[ct]);
      sacc[ct] = MFMA16(qf1, k1f, sacc[ct]);
    }

    // logits = S/8 + pos
    float p[4][4];
    const int dj = j0 - i0;
    if (dj >= 191) {
#pragma unroll
      for (int ct = 0; ct < 4; ++ct)
#pragma unroll
        for (int reg = 0; reg < 4; ++reg)
          p[ct][reg] = sacc[ct][reg] * 0.125f + rpR[reg];
    } else if (dj <= -191) {
#pragma unroll
      for (int ct = 0; ct < 4; ++ct)
#pragma unroll
        for (int reg = 0; reg < 4; ++reg)
          p[ct][reg] = sacc[ct][reg] * 0.125f + rpL[reg];
    } else {
#pragma unroll
      for (int ct = 0; ct < 4; ++ct) {
        int j = j0 + ct * 16 + l16;
#pragma unroll
        for (int reg = 0; reg < 4; ++reg) {
          int off = j - irow[reg];
          off = (off < -128) ? -128 : (off > 128 ? 128 : off);
          p[ct][reg] = sacc[ct][reg] * 0.125f + rpb[(size_t)irow[reg] * RSZ + off + 128];
        }
      }
    }

    // online softmax (rows live across the 16 lanes of each quad)
    float alpha[4];
#pragma unroll
    for (int reg = 0; reg < 4; ++reg) {
      float mm = fmaxf(fmaxf(p[0][reg], p[1][reg]), fmaxf(p[2][reg], p[3][reg]));
      mm = fmaxf(mm, __shfl_xor(mm, 1));
      mm = fmaxf(mm, __shfl_xor(mm, 2));
      mm = fmaxf(mm, __shfl_xor(mm, 4));
      mm = fmaxf(mm, __shfl_xor(mm, 8));
      float mnew = fmaxf(m_s[reg], mm);
      alpha[reg] = __expf(m_s[reg] - mnew);
      m_s[reg] = mnew;
    }
#pragma unroll
    for (int ct = 0; ct < 4; ++ct)
#pragma unroll
      for (int reg = 0; reg < 4; ++reg)
        p[ct][reg] = __expf(p[ct][reg] - m_s[reg]);
#pragma unroll
    for (int reg = 0; reg < 4; ++reg) {
      float rs = p[0][reg] + p[1][reg] + p[2][reg] + p[3][reg];
      rs += __shfl_xor(rs, 1);
      rs += __shfl_xor(rs, 2);
      rs += __shfl_xor(rs, 4);
      rs += __shfl_xor(rs, 8);
      l_s[reg] = l_s[reg] * alpha[reg] + rs;
    }
#pragma unroll
    for (int ct = 0; ct < 4; ++ct)
#pragma unroll
      for (int reg = 0; reg < 4; ++reg)
        oacc[ct][reg] *= alpha[reg];

    // P (C-layout) -> LDS -> A-layout fragments
#pragma unroll
    for (int ct = 0; ct < 4; ++ct)
#pragma unroll
      for (int reg = 0; reg < 4; ++reg)
        Ps[(wave * 16 + q4 * 4 + reg) * 72 + ct * 16 + l16] = f2bf(p[ct][reg]);
    __syncthreads();

    bfrag pf0 = *(const bfrag*)(Ps + (wave * 16 + l16) * 72 + q4 * 8);
    bfrag pf1 = *(const bfrag*)(Ps + (wave * 16 + l16) * 72 + 32 + q4 * 8);
#pragma unroll
    for (int ct = 0; ct < 4; ++ct) {
      bfrag v0f = *(const bfrag*)(Vs + (ct * 16 + l16) * 64 + q4 * 8);
      bfrag v1f = *(const bfrag*)(Vs + (ct * 16 + l16) * 64 + 32 + q4 * 8);
      oacc[ct] = MFMA16(pf0, v0f, oacc[ct]);
      oacc[ct] = MFMA16(pf1, v1f, oacc[ct]);
    }
    __syncthreads();
  }

  const int bidx = bh >> 4, hh = bh & 15;
#pragma unroll
  for (int reg = 0; reg < 4; ++reg) {
    float inv = 1.0f / l_s[reg];
#pragma unroll
    for (int ct = 0; ct < 4; ++ct)
      out[((size_t)bidx * SEQ + irow[reg]) * DMOD + hh * HDIM + ct * 16 + l16] =
          oacc[ct][reg] * inv;
  }
}

// ------------------- launch -------------------
extern "C" void kernel_launch(void* const* d_in, const int* in_sizes, int n_in,
                              void* d_out, int out_size, void* d_ws, size_t ws_size,
                              hipStream_t stream) {
  const float* x    = (const float*)d_in[0];  // [2,2048,1024]
  const float* Wqkv = (const float*)d_in[1];  // [3072,1024]
  const float* bqkv = (const float*)d_in[2];  // [3072]
  const float* Wr   = (const float*)d_in[3];  // [257,64]
  const float* br   = (const float*)d_in[4];  // [257]
  float* out = (float*)d_out;                 // [2,2048,1024] fp32

  char* ws = (char*)d_ws;
  unsigned short* xb  = (unsigned short*)(ws);               // 4096x1024 bf16 (8 MB)
  unsigned short* wb  = (unsigned short*)(ws + 8388608);     // 3072x1024 bf16 (6 MB)
  unsigned short* qb  = (unsigned short*)(ws + 14680064);    // 32x2048x64 bf16 (8 MB)
  unsigned short* kb  = (unsigned short*)(ws + 23068672);    // 32x2048x64 bf16 (8 MB)
  unsigned short* vtb = (unsigned short*)(ws + 31457280);    // 32x64x2048 bf16 (8 MB)
  unsigned short* wrb = (unsigned short*)(ws + 39845888);    // 272x64 bf16
  float*          rp  = (float*)(ws + 39880704);             // 32x2048x257 fp32 (67 MB)

  cast_bf16<<<4096, 256, 0, stream>>>(x, xb, 4096 * 1024);
  cast_bf16<<<3072, 256, 0, stream>>>(Wqkv, wb, 3072 * 1024);
  cast_wr<<<(RPADN * HDIM + 255) / 256, 256, 0, stream>>>(Wr, wrb);
  qkv_gemm<<<dim3(24, 32), 256, 0, stream>>>(xb, wb, bqkv, qb, kb, vtb);
  rp_gemm<<<1024, 256, 0, stream>>>(qb, wrb, br, rp);
  flash_attn<<<dim3(32, 32), 256, 0, stream>>>(qb, kb, vtb, rp, out);
}

// Round 3
// 265.893 us; speedup vs baseline: 1.1982x; 1.1982x over previous
//
#include <hip/hip_runtime.h>

typedef short bfrag __attribute__((ext_vector_type(8)));   // 8 bf16 (4 VGPRs)
typedef float f32x4 __attribute__((ext_vector_type(4)));   // MFMA accumulator

#define MFMA16(a, b, c) __builtin_amdgcn_mfma_f32_16x16x32_bf16((a), (b), (c), 0, 0, 0)

// b=2, s=2048, d=1024, h=16, hd=64, R=257, w=128, scale=sqrt(64)=8
#define SEQ   2048
#define DMOD  1024
#define NHEAD 16
#define HDIM  64
#define RSZ   257
#define RPADN 272     // 17*16, zero-padded
#define XN    (4096*1024)
#define WN    (3072*1024)
#define LOG2E 1.44269504f

__device__ __forceinline__ unsigned short f2bf(float f) {
  unsigned int u = __float_as_uint(f);
  u += 0x7FFFu + ((u >> 16) & 1u);   // round-to-nearest-even
  return (unsigned short)(u >> 16);
}
__device__ __forceinline__ float bf2f(unsigned short u) {
  return __uint_as_float(((unsigned int)u) << 16);
}
__device__ __forceinline__ float fexp2(float x) {
#if __has_builtin(__builtin_amdgcn_exp2f)
  return __builtin_amdgcn_exp2f(x);
#else
  return __expf(x * 0.69314718f);
#endif
}
__device__ __forceinline__ void gl2lds16(const void* g, void* l) {
  __builtin_amdgcn_global_load_lds(
      (__attribute__((address_space(1))) void*)(g),
      (__attribute__((address_space(3))) void*)(l), 16, 0, 0);
}

// ------------------- fused cast kernel -------------------
// region 0: x (4M), region 1: Wqkv (3M), region 2: Wr padded to [272][64]
__global__ __launch_bounds__(256) void cast_all(const float* __restrict__ x,
                                                const float* __restrict__ Wqkv,
                                                const float* __restrict__ Wr,
                                                unsigned short* __restrict__ xb,
                                                unsigned short* __restrict__ wb,
                                                unsigned short* __restrict__ wrb) {
  int i = (blockIdx.x * 256 + threadIdx.x) * 4;
  if (i < XN) {
    float4 v = *(const float4*)(x + i);
    ushort4 o; o.x = f2bf(v.x); o.y = f2bf(v.y); o.z = f2bf(v.z); o.w = f2bf(v.w);
    *(ushort4*)(xb + i) = o;
  } else if (i < XN + WN) {
    int j = i - XN;
    float4 v = *(const float4*)(Wqkv + j);
    ushort4 o; o.x = f2bf(v.x); o.y = f2bf(v.y); o.z = f2bf(v.z); o.w = f2bf(v.w);
    *(ushort4*)(wb + j) = o;
  } else {
    int j = i - XN - WN;      // 0 .. 17407, 4 at a time
    ushort4 o;
    unsigned short t[4];
#pragma unroll
    for (int k = 0; k < 4; ++k)
      t[k] = (j + k < RSZ * HDIM) ? f2bf(Wr[j + k]) : (unsigned short)0;
    o.x = t[0]; o.y = t[1]; o.z = t[2]; o.w = t[3];
    *(ushort4*)(wrb + j) = o;
  }
}

// ------------------- QKV projection GEMM -------------------
// C[m,n] = sum_k xb[m,k]*wb[n,k] + bqkv[n];  m<4096, n<3072, K=1024.
// 128x128 tile, BK=64, 256 thr. LDS tiles XOR-chunk-swizzled (chunk=8 shorts).
__global__ __launch_bounds__(256) void qkv_gemm(const unsigned short* __restrict__ xb,
                                                const unsigned short* __restrict__ wb,
                                                const float* __restrict__ bqkv,
                                                unsigned short* __restrict__ qb,
                                                unsigned short* __restrict__ kbuf,
                                                unsigned short* __restrict__ vb) {
  __shared__ unsigned short As[128 * 64];
  __shared__ unsigned short Bs[128 * 64];
  const int tid = threadIdx.x;
  const int m0 = blockIdx.y * 128, n0 = blockIdx.x * 128;
  const int wave = tid >> 6, lane = tid & 63;
  const int q4 = lane >> 4, l16 = lane & 15;
  const int wm = (wave & 1) * 64, wn = (wave >> 1) * 64;
  const int sw = l16 & 7;

  f32x4 acc[4][4];
#pragma unroll
  for (int rt = 0; rt < 4; ++rt)
#pragma unroll
    for (int ct = 0; ct < 4; ++ct) acc[rt][ct] = (f32x4){0.f, 0.f, 0.f, 0.f};

  for (int k0 = 0; k0 < DMOD; k0 += 64) {
#pragma unroll
    for (int it = 0; it < 4; ++it) {
      int ch = it * 256 + tid;
      int r = ch >> 3, cl = (ch & 7) ^ (r & 7);   // logical chunk for this slot
      gl2lds16(xb + (size_t)(m0 + r) * DMOD + k0 + cl * 8, As + ch * 8);
      gl2lds16(wb + (size_t)(n0 + r) * DMOD + k0 + cl * 8, Bs + ch * 8);
    }
    __syncthreads();
#pragma unroll
    for (int ks = 0; ks < 2; ++ks) {
      bfrag af[4], bf[4];
#pragma unroll
      for (int rt = 0; rt < 4; ++rt)
        af[rt] = *(const bfrag*)(As + (wm + rt * 16 + l16) * 64 + ((ks * 4 + q4) ^ sw) * 8);
#pragma unroll
      for (int ct = 0; ct < 4; ++ct)
        bf[ct] = *(const bfrag*)(Bs + (wn + ct * 16 + l16) * 64 + ((ks * 4 + q4) ^ sw) * 8);
#pragma unroll
      for (int rt = 0; rt < 4; ++rt)
#pragma unroll
        for (int ct = 0; ct < 4; ++ct)
          acc[rt][ct] = MFMA16(af[rt], bf[ct], acc[rt][ct]);
    }
    __syncthreads();
  }

#pragma unroll
  for (int rt = 0; rt < 4; ++rt) {
#pragma unroll
    for (int ct = 0; ct < 4; ++ct) {
      int n = n0 + wn + ct * 16 + l16;
      int hh = n / 192;
      int rem = n - hh * 192;
      int t = rem >> 6, dd = rem & 63;
      float bias = bqkv[n];
#pragma unroll
      for (int reg = 0; reg < 4; ++reg) {
        int m = m0 + wm + rt * 16 + q4 * 4 + reg;
        int bidx = m >> 11, sidx = m & 2047;
        unsigned short bv = f2bf(acc[rt][ct][reg] + bias);
        size_t hb = (size_t)(bidx * NHEAD + hh);
        size_t o = (hb * SEQ + sidx) * HDIM + dd;
        if (t == 0)      qb[o] = bv;
        else if (t == 1) kbuf[o] = bv;
        else             vb[o] = bv;   // coalesced; transposed later
      }
    }
  }
}

// ------------------- V transpose: vb[bh][s][64] -> vtb[bh][64][s] ---------
__global__ __launch_bounds__(256) void vtrans(const unsigned short* __restrict__ vb,
                                              unsigned short* __restrict__ vtb) {
  __shared__ unsigned short T[64 * 80];
  const int tid = threadIdx.x;
  const int s0 = blockIdx.x * 64;
  const int bh = blockIdx.y;
  const unsigned short* src = vb + ((size_t)bh * SEQ + s0) * HDIM;
#pragma unroll
  for (int it = 0; it < 2; ++it) {
    int idx = it * 256 + tid;
    int r = idx >> 3, c = idx & 7;
    *(uint4*)(&T[r * 80 + c * 8]) = *(const uint4*)(src + r * HDIM + c * 8);
  }
  __syncthreads();
#pragma unroll
  for (int it = 0; it < 2; ++it) {
    int idx = it * 256 + tid;
    int d = idx >> 3, c = idx & 7;
    unsigned short tmp[8];
#pragma unroll
    for (int k = 0; k < 8; ++k) tmp[k] = T[(c * 8 + k) * 80 + d];
    *(uint4*)(vtb + ((size_t)bh * HDIM + d) * SEQ + s0 + c * 8) = *(uint4*)tmp;
  }
}

// ------------------- rel-pos logits (pre-scaled by log2e, bf16 out) -------
__global__ __launch_bounds__(256) void rp_gemm(const unsigned short* __restrict__ qb,
                                               const unsigned short* __restrict__ wrb,
                                               const float* __restrict__ br,
                                               unsigned short* __restrict__ rp16) {
  __shared__ unsigned short WrS[RPADN * HDIM];  // 34816 B
  __shared__ unsigned short Qs[64 * HDIM];      // 8192 B
  const int tid = threadIdx.x;
  const size_t row0 = (size_t)blockIdx.x * 64;

  for (int i = tid; i < RPADN * HDIM / 8; i += 256)
    *(uint4*)(&WrS[i * 8]) = *(const uint4*)(&wrb[i * 8]);
  for (int i = tid; i < 512; i += 256)
    *(uint4*)(&Qs[i * 8]) = *(const uint4*)(&qb[row0 * HDIM + i * 8]);
  __syncthreads();

  const int wave = tid >> 6, lane = tid & 63;
  const int q4 = lane >> 4, l16 = lane & 15;

  bfrag af0 = *(const bfrag*)(Qs + (wave * 16 + l16) * 64 + q4 * 8);
  bfrag af1 = *(const bfrag*)(Qs + (wave * 16 + l16) * 64 + 32 + q4 * 8);

#pragma unroll 4
  for (int ct = 0; ct < 17; ++ct) {
    f32x4 acc = (f32x4){0.f, 0.f, 0.f, 0.f};
    bfrag b0 = *(const bfrag*)(WrS + (ct * 16 + l16) * 64 + q4 * 8);
    bfrag b1 = *(const bfrag*)(WrS + (ct * 16 + l16) * 64 + 32 + q4 * 8);
    acc = MFMA16(af0, b0, acc);
    acc = MFMA16(af1, b1, acc);
    int col = ct * 16 + l16;
    if (col < RSZ) {
      float bias = br[col];
#pragma unroll
      for (int reg = 0; reg < 4; ++reg) {
        size_t rr = row0 + wave * 16 + q4 * 4 + reg;
        rp16[rr * RSZ + col] = f2bf((acc[reg] + bias) * LOG2E);
      }
    }
  }
}

// ------------------- flash attention with relative position -------------------
// grid (32 qtiles, 32 bh); 256 thr; wave w owns Q rows [w*16, w*16+16); BN=64.
// All LDS tiles XOR-chunk-swizzled; softmax in exp2 domain.
__global__ __launch_bounds__(256) void flash_attn(const unsigned short* __restrict__ qb,
                                                  const unsigned short* __restrict__ kbuf,
                                                  const unsigned short* __restrict__ vtb,
                                                  const unsigned short* __restrict__ rp16,
                                                  float* __restrict__ out) {
  __shared__ unsigned short Ks[64 * 64];
  __shared__ unsigned short Vs[64 * 64];   // [d][j]
  __shared__ unsigned short Ps[64 * 64];

  const int tid = threadIdx.x;
  const int i0 = blockIdx.x * 64;
  const int bh = blockIdx.y;
  const int wave = tid >> 6, lane = tid & 63;
  const int q4 = lane >> 4, l16 = lane & 15;
  const int sw = l16 & 7;
  const float SC = 0.125f * LOG2E;

  const unsigned short* qrow = qb + ((size_t)bh * SEQ + i0 + wave * 16 + l16) * HDIM;
  bfrag qf0 = *(const bfrag*)(qrow + q4 * 8);
  bfrag qf1 = *(const bfrag*)(qrow + 32 + q4 * 8);

  const unsigned short* rpb = rp16 + (size_t)bh * SEQ * RSZ;
  int irow[4];
  float rpL[4], rpR[4];
#pragma unroll
  for (int reg = 0; reg < 4; ++reg) {
    irow[reg] = i0 + wave * 16 + q4 * 4 + reg;
    rpL[reg] = bf2f(rpb[(size_t)irow[reg] * RSZ]);
    rpR[reg] = bf2f(rpb[(size_t)irow[reg] * RSZ + 256]);
  }

  float m_s[4], l_s[4];
  f32x4 oacc[4];
#pragma unroll
  for (int reg = 0; reg < 4; ++reg) { m_s[reg] = -3.0e38f; l_s[reg] = 0.f; }
#pragma unroll
  for (int ct = 0; ct < 4; ++ct) oacc[ct] = (f32x4){0.f, 0.f, 0.f, 0.f};

  const unsigned short* kbase = kbuf + (size_t)bh * SEQ * HDIM;
  const unsigned short* vbase = vtb + (size_t)bh * HDIM * SEQ;

  for (int jt = 0; jt < 32; ++jt) {
    const int j0 = jt * 64;
#pragma unroll
    for (int it = 0; it < 2; ++it) {
      int ch = it * 256 + tid;
      int r = ch >> 3, cl = (ch & 7) ^ (r & 7);
      gl2lds16(kbase + (size_t)(j0 + r) * HDIM + cl * 8, Ks + ch * 8);
      gl2lds16(vbase + (size_t)r * SEQ + j0 + cl * 8, Vs + ch * 8);
    }
    __syncthreads();

    // S = Q K^T
    f32x4 sacc[4];
#pragma unroll
    for (int ct = 0; ct < 4; ++ct) {
      sacc[ct] = (f32x4){0.f, 0.f, 0.f, 0.f};
      bfrag k0f = *(const bfrag*)(Ks + (ct * 16 + l16) * 64 + (q4 ^ sw) * 8);
      bfrag k1f = *(const bfrag*)(Ks + (ct * 16 + l16) * 64 + ((4 + q4) ^ sw) * 8);
      sacc[ct] = MFMA16(qf0, k0f, sacc[ct]);
      sacc[ct] = MFMA16(qf1, k1f, sacc[ct]);
    }

    // logits2 = S * (log2e/8) + pos2
    float p[4][4];
    const int dj = j0 - i0;
    if (dj >= 191) {
#pragma unroll
      for (int ct = 0; ct < 4; ++ct)
#pragma unroll
        for (int reg = 0; reg < 4; ++reg)
          p[ct][reg] = sacc[ct][reg] * SC + rpR[reg];
    } else if (dj <= -191) {
#pragma unroll
      for (int ct = 0; ct < 4; ++ct)
#pragma unroll
        for (int reg = 0; reg < 4; ++reg)
          p[ct][reg] = sacc[ct][reg] * SC + rpL[reg];
    } else {
#pragma unroll
      for (int ct = 0; ct < 4; ++ct) {
        int j = j0 + ct * 16 + l16;
#pragma unroll
        for (int reg = 0; reg < 4; ++reg) {
          int off = j - irow[reg];
          off = (off < -128) ? -128 : (off > 128 ? 128 : off);
          p[ct][reg] = sacc[ct][reg] * SC + bf2f(rpb[(size_t)irow[reg] * RSZ + off + 128]);
        }
      }
    }

    // online softmax (exp2 domain); rows spread over 16 lanes of each quad
    float alpha[4];
#pragma unroll
    for (int reg = 0; reg < 4; ++reg) {
      float mm = fmaxf(fmaxf(p[0][reg], p[1][reg]), fmaxf(p[2][reg], p[3][reg]));
      mm = fmaxf(mm, __shfl_xor(mm, 1));
      mm = fmaxf(mm, __shfl_xor(mm, 2));
      mm = fmaxf(mm, __shfl_xor(mm, 4));
      mm = fmaxf(mm, __shfl_xor(mm, 8));
      float mnew = fmaxf(m_s[reg], mm);
      alpha[reg] = fexp2(m_s[reg] - mnew);
      m_s[reg] = mnew;
    }
#pragma unroll
    for (int ct = 0; ct < 4; ++ct)
#pragma unroll
      for (int reg = 0; reg < 4; ++reg)
        p[ct][reg] = fexp2(p[ct][reg] - m_s[reg]);
#pragma unroll
    for (int reg = 0; reg < 4; ++reg) {
      float rs = p[0][reg] + p[1][reg] + p[2][reg] + p[3][reg];
      rs += __shfl_xor(rs, 1);
      rs += __shfl_xor(rs, 2);
      rs += __shfl_xor(rs, 4);
      rs += __shfl_xor(rs, 8);
      l_s[reg] = l_s[reg] * alpha[reg] + rs;
    }
#pragma unroll
    for (int ct = 0; ct < 4; ++ct)
#pragma unroll
      for (int reg = 0; reg < 4; ++reg)
        oacc[ct][reg] *= alpha[reg];

    // P (C-layout) -> LDS (swizzled) -> A-layout frags. Wave-private rows: no barrier.
#pragma unroll
    for (int ct = 0; ct < 4; ++ct)
#pragma unroll
      for (int reg = 0; reg < 4; ++reg) {
        int row = wave * 16 + q4 * 4 + reg;
        int col = ct * 16 + l16;
        Ps[row * 64 + (((col >> 3) ^ (row & 7)) * 8) + (col & 7)] = f2bf(p[ct][reg]);
      }

    bfrag pf0 = *(const bfrag*)(Ps + (wave * 16 + l16) * 64 + (q4 ^ sw) * 8);
    bfrag pf1 = *(const bfrag*)(Ps + (wave * 16 + l16) * 64 + ((4 + q4) ^ sw) * 8);
#pragma unroll
    for (int ct = 0; ct < 4; ++ct) {
      bfrag v0f = *(const bfrag*)(Vs + (ct * 16 + l16) * 64 + (q4 ^ sw) * 8);
      bfrag v1f = *(const bfrag*)(Vs + (ct * 16 + l16) * 64 + ((4 + q4) ^ sw) * 8);
      oacc[ct] = MFMA16(pf0, v0f, oacc[ct]);
      oacc[ct] = MFMA16(pf1, v1f, oacc[ct]);
    }
    __syncthreads();
  }

  const int bidx = bh >> 4, hh = bh & 15;
#pragma unroll
  for (int reg = 0; reg < 4; ++reg) {
    float inv = 1.0f / l_s[reg];
#pragma unroll
    for (int ct = 0; ct < 4; ++ct)
      out[((size_t)bidx * SEQ + irow[reg]) * DMOD + hh * HDIM + ct * 16 + l16] =
          oacc[ct][reg] * inv;
  }
}

// ------------------- launch -------------------
extern "C" void kernel_launch(void* const* d_in, const int* in_sizes, int n_in,
                              void* d_out, int out_size, void* d_ws, size_t ws_size,
                              hipStream_t stream) {
  const float* x    = (const float*)d_in[0];  // [2,2048,1024]
  const float* Wqkv = (const float*)d_in[1];  // [3072,1024]
  const float* bqkv = (const float*)d_in[2];  // [3072]
  const float* Wr   = (const float*)d_in[3];  // [257,64]
  const float* br   = (const float*)d_in[4];  // [257]
  float* out = (float*)d_out;                 // [2,2048,1024] fp32

  char* ws = (char*)d_ws;
  unsigned short* xb   = (unsigned short*)(ws);               // 8 MB
  unsigned short* wb   = (unsigned short*)(ws + 8388608);     // 6 MB
  unsigned short* qb   = (unsigned short*)(ws + 14680064);    // 8 MB
  unsigned short* kb   = (unsigned short*)(ws + 23068672);    // 8 MB
  unsigned short* vb   = (unsigned short*)(ws + 31457280);    // 8 MB
  unsigned short* vtb  = (unsigned short*)(ws + 39845888);    // 8 MB
  unsigned short* wrb  = (unsigned short*)(ws + 48234496);    // 34816 B
  unsigned short* rp16 = (unsigned short*)(ws + 48269312);    // 33.7 MB (bf16, ×log2e)

  cast_all<<<7185, 256, 0, stream>>>(x, Wqkv, Wr, xb, wb, wrb);
  qkv_gemm<<<dim3(24, 32), 256, 0, stream>>>(xb, wb, bqkv, qb, kb, vb);
  vtrans<<<dim3(32, 32), 256, 0, stream>>>(vb, vtb);
  rp_gemm<<<1024, 256, 0, stream>>>(qb, wrb, br, rp16);
  flash_attn<<<dim3(32, 32), 256, 0, stream>>>(qb, kb, vtb, rp16, out);
}